// Round 7
// baseline (1104.518 us; speedup 1.0000x reference)
//
#include <hip/hip_runtime.h>
#include <math.h>

#define H 4096
#define E 64
#define T_TOTAL 32768
#define TB 64             // tokens per block (= lanes)
#define NT 512            // 8 waves = 8 expert octets
#define NEPT 8            // experts per thread
#define KC 64             // K per LDS x-chunk
#define NCH (H / KC)      // 64 chunks
#define KI (KC / 4)       // 16 K4-iterations per chunk
#define XP 68             // padded LDS row stride (floats, 16B-aligned)

// d_out layout (floats):
//   logits : [0, 2097152)       = [4,8192,64]
//   weights: [2097152, 2162688) = [32768,2]
//   indices: [2162688, 2228224) = [32768,2] (as float values)
#define OFF_W 2097152
#define OFF_I 2162688

__global__ __launch_bounds__(NT, 4)
void moe_router_kernel(const float* __restrict__ x,
                       const float* __restrict__ W,
                       float* __restrict__ out)
{
    // Double-buffered x chunk: [2][64 tokens][64 K + 4 pad] = 34,816 B.
    __shared__ float xb[2][TB][XP];

    const int tid  = threadIdx.x;
    const int lane = tid & 63;                                   // token
    const int wid  = __builtin_amdgcn_readfirstlane(tid >> 6);   // expert octet
    const int e0   = wid * NEPT;
    const int tok0 = blockIdx.x * TB;
    const int t    = tok0 + lane;

    // Wave-uniform W base -> scalar-load (SGPR) path. All in-loop offsets are
    // compile-time immediates off this one base.
    const float* w0 = W + (size_t)e0 * H;

    // x staging: flat float4-unit u of the [64][KC] chunk; thread covers
    // u = tid (token tid>>4) and u = tid + 512 (token (tid>>4)+32).
    const int st0 = tid >> 4;          // 0..31
    const int sk  = (tid & 15) * 4;    // 0..60
    const float* xs0 = x + (size_t)(tok0 + st0) * H + sk;
    const float* xs1 = x + (size_t)(tok0 + st0 + 32) * H + sk;

    float acc[NEPT];
#pragma unroll
    for (int e = 0; e < NEPT; ++e) acc[e] = 0.f;

    // ---- prologue: stage x chunk 0 ----
    {
        float4 s0 = *(const float4*)xs0;
        float4 s1 = *(const float4*)xs1;
        *(float4*)&xb[0][st0][sk]      = s0;
        *(float4*)&xb[0][st0 + 32][sk] = s1;
    }
    __syncthreads();

    for (int c = 0; c < NCH; ++c) {
        const int b = c & 1;

        // T14 issue-early: next x chunk global loads (land by the ds_write below)
        float4 sg0, sg1;
        if (c + 1 < NCH) {
            sg0 = *(const float4*)(xs0 + (c + 1) * KC);
            sg1 = *(const float4*)(xs1 + (c + 1) * KC);
        }

        // software pipeline: current x (VGPR) + current W (SGPR), prefetch i+1
        float4 xc = *(const float4*)&xb[b][lane][0];
        float4 wc[NEPT];
#pragma unroll
        for (int e = 0; e < NEPT; ++e)
            wc[e] = *(const float4*)(w0 + (size_t)e * H + c * KC);

#pragma unroll
        for (int i = 0; i < KI; ++i) {
            float4 xn, wn[NEPT];
            if (i + 1 < KI) {                       // compile-time after unroll
                xn = *(const float4*)&xb[b][lane][(i + 1) * 4];
#pragma unroll
                for (int e = 0; e < NEPT; ++e)
                    wn[e] = *(const float4*)(w0 + (size_t)e * H + c * KC + (i + 1) * 4);
            }
            // ascending-K chain, x/y/z/w order: bit-identical to R5/R6
#pragma unroll
            for (int e = 0; e < NEPT; ++e) {
                acc[e] = fmaf(xc.x, wc[e].x, acc[e]);
                acc[e] = fmaf(xc.y, wc[e].y, acc[e]);
                acc[e] = fmaf(xc.z, wc[e].z, acc[e]);
                acc[e] = fmaf(xc.w, wc[e].w, acc[e]);
            }
            if (i + 1 < KI) {
                xc = xn;
#pragma unroll
                for (int e = 0; e < NEPT; ++e) wc[e] = wn[e];
            }
        }

        // write staged x for chunk c+1 into the other buffer, then barrier
        if (c + 1 < NCH) {
            *(float4*)&xb[b ^ 1][st0][sk]      = sg0;
            *(float4*)&xb[b ^ 1][st0 + 32][sk] = sg1;
        }
        __syncthreads();
    }

    // ---- logits out (from registers, bit-identical chain) ----
    float* orow = out + (size_t)t * E + e0;
    {
        float4 v0; v0.x = acc[0]; v0.y = acc[1]; v0.z = acc[2]; v0.w = acc[3];
        float4 v1; v1.x = acc[4]; v1.y = acc[5]; v1.z = acc[6]; v1.w = acc[7];
        *(float4*)(orow)     = v0;
        *(float4*)(orow + 4) = v1;
    }

    // ---- exchange for top-2 (reuse xb; stride 65) ----
    float* lt = &xb[0][0][0];          // 64 x 65 tile
#pragma unroll
    for (int e = 0; e < NEPT; ++e)
        lt[lane * 65 + e0 + e] = acc[e];
    __syncthreads();

    if (tid < TB) {
        const float* row = lt + tid * 65;
        float v1 = -INFINITY, v2 = -INFINITY;
        int i1 = 0, i2 = 0;
        for (int e = 0; e < E; ++e) {
            float v = row[e];
            if (v > v1)      { v2 = v1; i2 = i1; v1 = v; i1 = e; }
            else if (v > v2) { v2 = v;  i2 = e; }
        }
        // softmax -> top2 -> renorm == sigmoid of logit gap (Z cancels)
        float ee = expf(v2 - v1);
        float w1 = 1.0f / (1.0f + ee);
        float w2 = ee * w1;

        const size_t tok = (size_t)tok0 + tid;
        out[OFF_W + tok * 2]     = w1;
        out[OFF_W + tok * 2 + 1] = w2;
        out[OFF_I + tok * 2]     = (float)i1;
        out[OFF_I + tok * 2 + 1] = (float)i2;
    }
}

extern "C" void kernel_launch(void* const* d_in, const int* in_sizes, int n_in,
                              void* d_out, int out_size, void* d_ws, size_t ws_size,
                              hipStream_t stream) {
    const float* x = (const float*)d_in[0];
    const float* W = (const float*)d_in[1];
    float* out = (float*)d_out;

    dim3 grid(T_TOTAL / TB);   // 512 blocks -> 2 blocks/CU, 4 waves/SIMD
    dim3 block(NT);
    moe_router_kernel<<<grid, block, 0, stream>>>(x, W, out);
}

// Round 8
// 811.613 us; speedup vs baseline: 1.3609x; 1.3609x over previous
//
#include <hip/hip_runtime.h>
#include <math.h>

#define H 4096
#define E 64
#define T_TOTAL 32768
#define TBT 128           // tokens per block (64 lanes x 2 tokens/thread)
#define NT 512            // 8 waves = 8 expert octets
#define NEPT 8            // experts per thread (wave-uniform octet -> SGPR W)

// d_out layout (floats):
//   logits : [0, 2097152)       = [4,8192,64]
//   weights: [2097152, 2162688) = [32768,2]
//   indices: [2162688, 2228224) = [32768,2] (as float values)
#define OFF_W 2097152
#define OFF_I 2162688

// Load one K4 slab of the wave's 8 experts into DST (uniform addr -> s_load).
#define WLOAD(DST, KOFF)                                                     \
    do {                                                                     \
        _Pragma("unroll")                                                    \
        for (int e = 0; e < NEPT; ++e)                                       \
            DST[e] = *(const float4*)(w0 + (size_t)e * H + (KOFF));          \
    } while (0)

// One K4 step: issue next W slab (if PW), then 64 fmaf (2 tokens x 8 experts).
// Per (token,expert) the chain is ascending K, x/y/z/w order — bit-identical
// to the verified R1/R5/R6 kernels (index tie-safety on the fixed dataset).
#define STEP(WC, WN, X0, X1, KNEXT, PW)                                      \
    do {                                                                     \
        if (PW) WLOAD(WN, KNEXT);                                            \
        _Pragma("unroll")                                                    \
        for (int e = 0; e < NEPT; ++e) {                                     \
            acc0[e] = fmaf((X0).x, WC[e].x, acc0[e]);                        \
            acc0[e] = fmaf((X0).y, WC[e].y, acc0[e]);                        \
            acc0[e] = fmaf((X0).z, WC[e].z, acc0[e]);                        \
            acc0[e] = fmaf((X0).w, WC[e].w, acc0[e]);                        \
            acc1[e] = fmaf((X1).x, WC[e].x, acc1[e]);                        \
            acc1[e] = fmaf((X1).y, WC[e].y, acc1[e]);                        \
            acc1[e] = fmaf((X1).z, WC[e].z, acc1[e]);                        \
            acc1[e] = fmaf((X1).w, WC[e].w, acc1[e]);                        \
        }                                                                    \
    } while (0)

// One 32-K iteration: 8 K4 steps (wA/wB alternate, parity-consistent), x
// refilled mid-iteration at 4-8 step (512-1024 cyc) prefetch distance.
#define IT_BODY(PREF)                                                        \
    do {                                                                     \
        STEP(wA, wB, xa0[0], xa1[0], kA + 4,  1);                            \
        STEP(wB, wA, xa0[1], xa1[1], kA + 8,  1);                            \
        STEP(wA, wB, xa0[2], xa1[2], kA + 12, 1);                            \
        STEP(wB, wA, xa0[3], xa1[3], kA + 16, 1);                            \
        if (PREF) {                                                          \
            _Pragma("unroll")                                                \
            for (int j = 0; j < 4; ++j) {                                    \
                xa0[j] = *(const float4*)(xr0 + kA + 32 + 4 * j);            \
                xa1[j] = *(const float4*)(xr1 + kA + 32 + 4 * j);            \
            }                                                                \
        }                                                                    \
        STEP(wA, wB, xb0[0], xb1[0], kA + 20, 1);                            \
        STEP(wB, wA, xb0[1], xb1[1], kA + 24, 1);                            \
        STEP(wA, wB, xb0[2], xb1[2], kA + 28, 1);                            \
        STEP(wB, wA, xb0[3], xb1[3], kA + 32, PREF);                         \
        if (PREF) {                                                          \
            _Pragma("unroll")                                                \
            for (int j = 0; j < 4; ++j) {                                    \
                xb0[j] = *(const float4*)(xr0 + kA + 48 + 4 * j);            \
                xb1[j] = *(const float4*)(xr1 + kA + 48 + 4 * j);            \
            }                                                                \
        }                                                                    \
    } while (0)

__global__ __launch_bounds__(NT, 2)   // ~100 VGPR live; cap 256 -> no spill
void moe_router_kernel(const float* __restrict__ x,
                       const float* __restrict__ W,
                       float* __restrict__ out)
{
    __shared__ float lt[TBT * 65];    // epilogue-only exchange tile (33 KB)

    const int tid  = threadIdx.x;
    const int lane = tid & 63;                                   // token
    const int wid  = __builtin_amdgcn_readfirstlane(tid >> 6);   // expert octet
    const int e0   = wid * NEPT;
    const int tok0 = blockIdx.x * TBT;
    const int t0   = tok0 + lane;                                // token A
    const int t1   = t0 + 64;                                    // token B

    const float* xr0 = x + (size_t)t0 * H;
    const float* xr1 = x + (size_t)t1 * H;
    const float* w0  = W + (size_t)e0 * H;    // wave-uniform -> s_load path

    float acc0[NEPT], acc1[NEPT];
#pragma unroll
    for (int e = 0; e < NEPT; ++e) { acc0[e] = 0.f; acc1[e] = 0.f; }

    // prime x phases: xa = K[0,16), xb = K[16,32)
    float4 xa0[4], xa1[4], xb0[4], xb1[4];
#pragma unroll
    for (int j = 0; j < 4; ++j) {
        xa0[j] = *(const float4*)(xr0 + 4 * j);
        xa1[j] = *(const float4*)(xr1 + 4 * j);
        xb0[j] = *(const float4*)(xr0 + 16 + 4 * j);
        xb1[j] = *(const float4*)(xr1 + 16 + 4 * j);
    }

    // prime W: K4 @ 0
    float4 wA[NEPT], wB[NEPT];
    WLOAD(wA, 0);

    for (int it = 0; it < H / 32 - 1; ++it) {
        const int kA = it * 32;
        IT_BODY(1);
    }
    {
        const int kA = H - 32;
        IT_BODY(0);
    }

    // ---- logits out (from registers, bit-identical chain) ----
    {
        float* o0 = out + (size_t)t0 * E + e0;
        float* o1 = out + (size_t)t1 * E + e0;
        float4 v;
        v.x = acc0[0]; v.y = acc0[1]; v.z = acc0[2]; v.w = acc0[3];
        *(float4*)o0 = v;
        v.x = acc0[4]; v.y = acc0[5]; v.z = acc0[6]; v.w = acc0[7];
        *(float4*)(o0 + 4) = v;
        v.x = acc1[0]; v.y = acc1[1]; v.z = acc1[2]; v.w = acc1[3];
        *(float4*)o1 = v;
        v.x = acc1[4]; v.y = acc1[5]; v.z = acc1[6]; v.w = acc1[7];
        *(float4*)(o1 + 4) = v;
    }

    // ---- exchange for top-2 ----
#pragma unroll
    for (int e = 0; e < NEPT; ++e) {
        lt[lane * 65 + e0 + e]        = acc0[e];
        lt[(lane + 64) * 65 + e0 + e] = acc1[e];
    }
    __syncthreads();

    if (tid < TBT) {
        const float* row = lt + tid * 65;
        float v1 = -INFINITY, v2 = -INFINITY;
        int i1 = 0, i2 = 0;
        for (int e = 0; e < E; ++e) {
            float v = row[e];
            if (v > v1)      { v2 = v1; i2 = i1; v1 = v; i1 = e; }
            else if (v > v2) { v2 = v;  i2 = e; }
        }
        // softmax -> top2 -> renorm == sigmoid of logit gap (Z cancels)
        float ee = expf(v2 - v1);
        float w1 = 1.0f / (1.0f + ee);
        float w2 = ee * w1;

        const size_t tok = (size_t)tok0 + tid;
        out[OFF_W + tok * 2]     = w1;
        out[OFF_W + tok * 2 + 1] = w2;
        out[OFF_I + tok * 2]     = (float)i1;
        out[OFF_I + tok * 2 + 1] = (float)i2;
    }
}

extern "C" void kernel_launch(void* const* d_in, const int* in_sizes, int n_in,
                              void* d_out, int out_size, void* d_ws, size_t ws_size,
                              hipStream_t stream) {
    const float* x = (const float*)d_in[0];
    const float* W = (const float*)d_in[1];
    float* out = (float*)d_out;

    dim3 grid(T_TOTAL / TBT);   // 256 blocks -> 1 block/CU, 2 waves/SIMD
    dim3 block(NT);
    moe_router_kernel<<<grid, block, 0, stream>>>(x, W, out);
}